// Round 3
// 475.668 us; speedup vs baseline: 1.1465x; 1.1465x over previous
//
#include <hip/hip_runtime.h>

// Problem constants (from reference: shape (2,1,384,1248), MAXDISP=128, C=1)
#define NB 2
#define HH 384
#define WW 1248
#define W4 (WW / 4)        // 312 float4 per row
#define MAXDISP 128
#define DPT 4              // disparities per thread

// Clang-native 4-float vector: required by __builtin_nontemporal_store
// (HIP's float4 is a class type the builtin rejects).
using f32x4 = __attribute__((ext_vector_type(4))) float;

// out[n, d, y, x] = x >= d ? |img1[n,0,y,x] - img2[n,0,y,x-d]| : 0
// Output layout: ((n*128 + d)*384 + y)*1248 + x   (C==1)
//
// Traffic-bound kernel. v2: d-blocking — each thread produces the same
// (y, x..x+3) strip for 4 consecutive disparities d0..d0+3, reusing one
// img1 vector and two aligned img2 vectors (register shift network).
// Read:write traffic drops 2:1 -> 0.75:1.
//
// Key alignment fact: x = 4*x4 and d0 = 4*blockIdx.y are both multiples
// of 4, so s = x - d0 is a multiple of 4:
//   s <= -4 : all 16 outputs masked (store zeros, skip loads)
//   s == 0  : hi = row2[s..s+3] valid; all lo-sourced elements masked
//   s >= 4  : lo and hi both fully valid
// -> no misaligned loads, no partial-validity edge case, branchless masks.
__global__ __launch_bounds__(256) void cost_volume_kernel(
    const float* __restrict__ img1,
    const float* __restrict__ img2,
    float* __restrict__ out)
{
    const int d0 = blockIdx.y * DPT;    // disparity group base: 0,4,...,124
    const int n  = blockIdx.z;          // batch 0..1

    // flat index over (y, x4) for this (n, d-group) slice
    const int idx = blockIdx.x * 256 + threadIdx.x;   // 0 .. H*W4-1 (468*256 exact)
    const int x4  = idx % W4;
    const int y   = idx / W4;
    const int x   = x4 * 4;

    const float* __restrict__ row1 = img1 + (n * HH + y) * WW;
    const float* __restrict__ row2 = img2 + (n * HH + y) * WW;

    // output vector pointers: ((n*D + d0+dd)*H*W4) + idx, stride H*W4 per dd
    const size_t dstride = (size_t)HH * W4;
    f32x4* o0 = (f32x4*)out + (size_t)(n * MAXDISP + d0) * dstride + (size_t)idx;

    const int s = x - d0;               // shifted source col, multiple of 4

    if (s < 0) {
        // s <= -4: every output in this thread is left of the valid region
        const f32x4 z = {0.f, 0.f, 0.f, 0.f};
        __builtin_nontemporal_store(z, o0);
        __builtin_nontemporal_store(z, o0 + dstride);
        __builtin_nontemporal_store(z, o0 + 2 * dstride);
        __builtin_nontemporal_store(z, o0 + 3 * dstride);
        return;
    }

    const f32x4 a  = *(const f32x4*)(row1 + x);        // img1[x..x+3]
    const f32x4 hi = *(const f32x4*)(row2 + s);        // img2[s..s+3]  (s >= 0)
    const bool  m4 = (s >= 4);                         // lo-window validity
    const f32x4 lo = *(const f32x4*)(row2 + max(s - 4, 0)); // img2[s-4..s-1]

    f32x4 o;

    // dd = 0: indices s..s+3, all valid
    o.x = fabsf(a.x - hi.x);
    o.y = fabsf(a.y - hi.y);
    o.z = fabsf(a.z - hi.z);
    o.w = fabsf(a.w - hi.w);
    __builtin_nontemporal_store(o, o0);

    // dd = 1: indices s-1..s+2 -> lo.w, hi.x, hi.y, hi.z
    o.x = m4 ? fabsf(a.x - lo.w) : 0.f;
    o.y = fabsf(a.y - hi.x);
    o.z = fabsf(a.z - hi.y);
    o.w = fabsf(a.w - hi.z);
    __builtin_nontemporal_store(o, o0 + dstride);

    // dd = 2: indices s-2..s+1 -> lo.z, lo.w, hi.x, hi.y
    o.x = m4 ? fabsf(a.x - lo.z) : 0.f;
    o.y = m4 ? fabsf(a.y - lo.w) : 0.f;
    o.z = fabsf(a.z - hi.x);
    o.w = fabsf(a.w - hi.y);
    __builtin_nontemporal_store(o, o0 + 2 * dstride);

    // dd = 3: indices s-3..s -> lo.y, lo.z, lo.w, hi.x
    o.x = m4 ? fabsf(a.x - lo.y) : 0.f;
    o.y = m4 ? fabsf(a.y - lo.z) : 0.f;
    o.z = m4 ? fabsf(a.z - lo.w) : 0.f;
    o.w = fabsf(a.w - hi.x);
    __builtin_nontemporal_store(o, o0 + 3 * dstride);
}

extern "C" void kernel_launch(void* const* d_in, const int* in_sizes, int n_in,
                              void* d_out, int out_size, void* d_ws, size_t ws_size,
                              hipStream_t stream) {
    const float* img1 = (const float*)d_in[0];
    const float* img2 = (const float*)d_in[1];
    float* out = (float*)d_out;

    // H*W4 = 384*312 = 119808 = 468 * 256 exactly
    dim3 grid((HH * W4) / 256, MAXDISP / DPT, NB);
    dim3 block(256);
    cost_volume_kernel<<<grid, block, 0, stream>>>(img1, img2, out);
}